// Round 21
// baseline (710.988 us; speedup 1.0000x reference)
//
#include <hip/hip_runtime.h>
#include <hip/hip_bf16.h>

#define S_ 1024
#define H_ 2048
#define NH_ 32
#define NKV_ 4
#define HD_ 128
#define NE_ 32
#define TOPK_ 8
#define I_ 768
#define EPS_ 1e-6f
#define QS_ 5120   // fused qkv row stride: 4096 q + 512 k + 512 v
#define BK2 32

typedef __bf16 bf16_t;
typedef __bf16 bf16x4v __attribute__((ext_vector_type(4)));
typedef __bf16 bf16x8 __attribute__((ext_vector_type(8)));
typedef float f32x4 __attribute__((ext_vector_type(4)));
typedef float f32x16 __attribute__((ext_vector_type(16)));
typedef unsigned short u16_t;
typedef unsigned int uint2v __attribute__((ext_vector_type(2)));
typedef unsigned int uint4v __attribute__((ext_vector_type(4)));

static __device__ __forceinline__ u16_t f2u(float x) {
  return __builtin_bit_cast(u16_t, (__bf16)x);
}
static __device__ __forceinline__ float u2f(u16_t u) {
  return (float)__builtin_bit_cast(__bf16, u);
}

// async global->LDS 16B per lane; dest wave-uniform base + lane*16
static __device__ __forceinline__ void gload16(const bf16_t* g, bf16_t* l) {
  __builtin_amdgcn_global_load_lds(
      (const __attribute__((address_space(1))) unsigned int*)g,
      (__attribute__((address_space(3))) unsigned int*)l, 16, 0, 0);
}

// per-lane element offset inside a 1KB [16][32] k-step tile (XOR chunk swizzle)
static __device__ __forceinline__ int tile_lane_off(int lane) {
  return (lane >> 2) * 32 + (((lane & 3) ^ ((lane >> 3) & 3)) << 3);
}

// ---------------- RMSNorm over H: fp32 (optional) + bf16 outputs ----------------
template <bool WF32>
__global__ __launch_bounds__(256) void rmsnorm2_k(const float* __restrict__ x,
                                                  const float* __restrict__ w,
                                                  float* __restrict__ outf,
                                                  bf16_t* __restrict__ outb) {
  int r = blockIdx.x, tid = threadIdx.x;
  const float* xr = x + (size_t)r * H_;
  f32x4 a = *(const f32x4*)(xr + tid * 8);
  f32x4 b = *(const f32x4*)(xr + tid * 8 + 4);
  float ss = 0.f;
#pragma unroll
  for (int i = 0; i < 4; ++i) ss += a[i] * a[i] + b[i] * b[i];
#pragma unroll
  for (int m = 1; m < 64; m <<= 1) ss += __shfl_xor(ss, m);
  __shared__ float wsum[4];
  if ((tid & 63) == 0) wsum[tid >> 6] = ss;
  __syncthreads();
  ss = wsum[0] + wsum[1] + wsum[2] + wsum[3];
  float inv = rsqrtf(ss * (1.0f / H_) + EPS_);
  f32x4 w0 = *(const f32x4*)(w + tid * 8);
  f32x4 w1 = *(const f32x4*)(w + tid * 8 + 4);
  f32x4 o0, o1;
#pragma unroll
  for (int i = 0; i < 4; ++i) { o0[i] = a[i] * inv * w0[i]; o1[i] = b[i] * inv * w1[i]; }
  if constexpr (WF32) {
    *(f32x4*)(outf + (size_t)r * H_ + tid * 8) = o0;
    *(f32x4*)(outf + (size_t)r * H_ + tid * 8 + 4) = o1;
  }
  bf16x8 ob;
#pragma unroll
  for (int i = 0; i < 4; ++i) { ob[i] = (__bf16)o0[i]; ob[i + 4] = (__bf16)o1[i]; }
  *(bf16x8*)(outb + (size_t)r * H_ + tid * 8) = ob;
}

// ---------------- weight transpose + bf16 + tile pack ----------------
// in[R][C] fp32 (R = K dim, C = N dim) -> out tiles [C/16][R/32][16][32] bf16.
__global__ __launch_bounds__(256) void transp3_k(const float* __restrict__ in,
                                                 bf16_t* __restrict__ out, int R, int C) {
  __shared__ float tile[64][65];  // [k][n]
  size_t z = (size_t)blockIdx.z * R * C;
  int tx = threadIdx.x & 15, ty = threadIdx.x >> 4;
  int r0 = blockIdx.y * 64, c0 = blockIdx.x * 64;
#pragma unroll
  for (int i = 0; i < 4; ++i) {
    f32x4 v = *(const f32x4*)(in + z + (size_t)(r0 + ty + i * 16) * C + c0 + tx * 4);
    tile[ty + i * 16][tx * 4 + 0] = v[0];
    tile[ty + i * 16][tx * 4 + 1] = v[1];
    tile[ty + i * 16][tx * 4 + 2] = v[2];
    tile[ty + i * 16][tx * 4 + 3] = v[3];
  }
  __syncthreads();
  int KT = R >> 5;
  int flat = threadIdx.x * 16;
  int lt = flat >> 9;
  int within = flat & 511;
  int nr = within >> 5;
  int kc = within & 31;
  int tn = lt >> 1, tk = lt & 1;
  bf16x8 o0, o1;
#pragma unroll
  for (int j = 0; j < 8; ++j) o0[j] = (bf16_t)tile[tk * 32 + kc + j][tn * 16 + nr];
#pragma unroll
  for (int j = 0; j < 8; ++j) o1[j] = (bf16_t)tile[tk * 32 + kc + 8 + j][tn * 16 + nr];
  size_t tidx = ((size_t)((c0 >> 4) + tn) * KT + (r0 >> 5) + tk) << 9;
  *(bf16x8*)(out + z + tidx + nr * 32 + kc) = o0;
  *(bf16x8*)(out + z + tidx + nr * 32 + kc + 8) = o1;
}

// ---------------- dense GEMM v2: BK=128 supersteps, deep issue ----------------
// BMT=128, 8 waves (WM*WN must equal 8); per superstep each wave issues gload16
// back-to-back, one barrier, 4 MFMA sub-steps (k order = former BK2 sequence).
template <int BNT, int WM, int WN, typename TC, bool RESID>
__global__ __launch_bounds__(512) void gemmd2_k(
    const bf16_t* __restrict__ A, const bf16_t* __restrict__ Bt,
    const float* __restrict__ resid, TC* __restrict__ C, int M, int N, int K) {
  constexpr int BMT = 128, SUBS = 4;
  constexpr int MI = BMT / WM / 16;
  constexpr int NI = BNT / WN / 16;
  constexpr int NBT = BNT / 16;   // B row-tiles (<=8)
  static_assert(WM * WN == 8, "8 waves");
  __shared__ __align__(16) bf16_t As[SUBS][BMT][BK2];   // 32KB
  __shared__ __align__(16) bf16_t Bs[SUBS][BNT][BK2];
  int tid = threadIdx.x, lane = tid & 63, w = tid >> 6;
  int m0 = blockIdx.x * BMT, n0 = blockIdx.y * BNT;
  int srow = lane >> 2;
  int schunk = ((lane & 3) ^ ((lane >> 3) & 3)) * 8;
  int tloff = tile_lane_off(lane);
  int fr = lane & 15, g = lane >> 4;
  int rk = (g ^ ((fr >> 1) & 3)) * 8;
  int wm = w / WN, wn = w % WN;
  int rbase0 = wm * (BMT / WM), cbase0 = wn * (BNT / WN);
  int KT = K >> 5;
  int SS = K >> 7;
  const bf16_t* asrc = A + (size_t)(m0 + w * 16 + srow) * K + schunk;
  bool hasB = (w < NBT);
  const bf16_t* bsrc = nullptr;
  if (hasB) bsrc = Bt + ((size_t)((n0 + w * 16) >> 4) * KT) * 512 + tloff;
  f32x4 acc[MI][NI] = {};
  for (int ss = 0; ss < SS; ++ss) {
    int kbase = ss * 128;
#pragma unroll
    for (int sub = 0; sub < SUBS; ++sub)
      gload16(asrc + kbase + sub * BK2, &As[sub][w * 16][0]);
    if (hasB) {
#pragma unroll
      for (int sub = 0; sub < SUBS; ++sub)
        gload16(bsrc + (size_t)(ss * SUBS + sub) * 512, &Bs[sub][w * 16][0]);
    }
    __syncthreads();
#pragma unroll
    for (int sub = 0; sub < SUBS; ++sub) {
      bf16x8 af[MI], bf[NI];
#pragma unroll
      for (int i = 0; i < MI; ++i) af[i] = *(const bf16x8*)&As[sub][rbase0 + i * 16 + fr][rk];
#pragma unroll
      for (int i = 0; i < NI; ++i) bf[i] = *(const bf16x8*)&Bs[sub][cbase0 + i * 16 + fr][rk];
#pragma unroll
      for (int mi = 0; mi < MI; ++mi)
#pragma unroll
        for (int ni = 0; ni < NI; ++ni)
          acc[mi][ni] = __builtin_amdgcn_mfma_f32_16x16x32_bf16(af[mi], bf[ni], acc[mi][ni], 0, 0, 0);
    }
    __syncthreads();
  }
  int rbase = g * 4;
#pragma unroll
  for (int mi = 0; mi < MI; ++mi)
#pragma unroll
    for (int ni = 0; ni < NI; ++ni)
#pragma unroll
      for (int r = 0; r < 4; ++r) {
        int gi = m0 + rbase0 + mi * 16 + rbase + r;
        int gc = n0 + cbase0 + ni * 16 + fr;
        float v = acc[mi][ni][r];
        if constexpr (RESID) v += resid[(size_t)gi * N + gc];
        C[(size_t)gi * N + gc] = (TC)v;
      }
}

// ---------------- persistent expert GEMM v5: BMT=256, BK=64 supersteps, 48KB LDS ----------------
// Halved B re-reads (256-row m-slots). SUBS=2; per wave 6 back-to-back gload16.
template <int BNT, typename TC, bool GATHER, bool SCALE, bool DUAL>
__global__ __launch_bounds__(512) void gemme5_k(
    const bf16_t* __restrict__ A, const bf16_t* __restrict__ B1g,
    const bf16_t* __restrict__ B2g, TC* __restrict__ C, bf16_t* __restrict__ act,
    const float* __restrict__ wlist, const int* __restrict__ counts,
    const int* __restrict__ offsets, const int* __restrict__ toklist,
    const int* __restrict__ mslots, const int* __restrict__ meta,
    int* __restrict__ qhead, int NTN, int N, int K) {
  constexpr int BMT = 256;
  constexpr int SUBS = 2;
  constexpr int WM = 4, WN = 2;
  constexpr int MI = BMT / WM / 16;   // 4
  constexpr int NI = BNT / WN / 16;   // 64->2, 128->4
  constexpr int BNTT = BNT * (DUAL ? 2 : 1);   // 128 both
  static_assert(BNTT / 16 == 8, "B tile split");
  __shared__ __align__(16) bf16_t As[SUBS][BMT][BK2];   // 32KB
  __shared__ __align__(16) bf16_t Bs[SUBS][BNTT][BK2];  // 16KB
  __shared__ int s_w;
  int tid = threadIdx.x, lane = tid & 63, w = tid >> 6;
  int srow = lane >> 2;
  int schunk = ((lane & 3) ^ ((lane >> 3) & 3)) * 8;
  int tloff = tile_lane_off(lane);
  int fr = lane & 15, g = lane >> 4;
  int rk = (g ^ ((fr >> 1) & 3)) * 8;
  int wm = w / WN, wn = w % WN;
  int rbase0 = wm * (BMT / WM), cbase0 = wn * (BNT / WN);
  int KT = K >> 5;
  int SS = K >> 6;   // supersteps of 64 k
  int total = meta[0] * NTN;
  for (;;) {
    if (tid == 0) s_w = atomicAdd(qhead, 1);
    __syncthreads();
    int wk = s_w;
    if (wk >= total) return;
    int ms = mslots[wk / NTN];
    int n0 = (wk % NTN) * BNT;
    int e = ms >> 8, m0 = (ms & 255) * BMT;
    int cnt = counts[e], off = offsets[e];
    size_t bs = (size_t)K * N;
    const bf16_t* B1 = B1g + (size_t)e * bs;
    const bf16_t* B2 = DUAL ? (B2g + (size_t)e * bs) : nullptr;
    // A: two 16-row tiles per wave (rows w*32 .. w*32+31)
    const bf16_t* asrc[2];
#pragma unroll
    for (int i = 0; i < 2; ++i) {
      int gr = min(m0 + w * 32 + i * 16 + srow, cnt - 1);
      size_t grow;
      if constexpr (GATHER) grow = (size_t)toklist[e * S_ + gr];
      else grow = (size_t)(off + gr);
      asrc[i] = A + grow * (size_t)K + schunk;
    }
    // B: one 16-row tile per wave within BNTT
    const bf16_t* bsrc;
    int brow16 = w * 16;
    {
      const bf16_t* Bb = (brow16 < BNT) ? B1 : B2;
      int rr = (brow16 < BNT) ? brow16 : brow16 - BNT;
      bsrc = Bb + ((size_t)((n0 + rr) >> 4) * KT) * 512 + tloff;
    }
    f32x4 acc1[MI][NI] = {};
    f32x4 acc2[DUAL ? MI : 1][DUAL ? NI : 1] = {};
    for (int ss = 0; ss < SS; ++ss) {
      int kbase = ss * 64;
      // deep issue: 6 gload16 per wave, no intervening waits
#pragma unroll
      for (int i = 0; i < 2; ++i)
#pragma unroll
        for (int sub = 0; sub < SUBS; ++sub)
          gload16(asrc[i] + kbase + sub * BK2, &As[sub][w * 32 + i * 16][0]);
#pragma unroll
      for (int sub = 0; sub < SUBS; ++sub)
        gload16(bsrc + (size_t)(ss * SUBS + sub) * 512, &Bs[sub][brow16][0]);
      __syncthreads();
#pragma unroll
      for (int sub = 0; sub < SUBS; ++sub) {
        bf16x8 af[MI], b1f[NI], b2f[DUAL ? NI : 1];
#pragma unroll
        for (int i = 0; i < MI; ++i) af[i] = *(const bf16x8*)&As[sub][rbase0 + i * 16 + fr][rk];
#pragma unroll
        for (int i = 0; i < NI; ++i) b1f[i] = *(const bf16x8*)&Bs[sub][cbase0 + i * 16 + fr][rk];
        if constexpr (DUAL) {
#pragma unroll
          for (int i = 0; i < NI; ++i) b2f[i] = *(const bf16x8*)&Bs[sub][BNT + cbase0 + i * 16 + fr][rk];
        }
#pragma unroll
        for (int mi = 0; mi < MI; ++mi)
#pragma unroll
          for (int ni = 0; ni < NI; ++ni) {
            acc1[mi][ni] = __builtin_amdgcn_mfma_f32_16x16x32_bf16(af[mi], b1f[ni], acc1[mi][ni], 0, 0, 0);
            if constexpr (DUAL)
              acc2[mi][ni] = __builtin_amdgcn_mfma_f32_16x16x32_bf16(af[mi], b2f[ni], acc2[mi][ni], 0, 0, 0);
          }
      }
      __syncthreads();
    }
    int rbase = g * 4;
#pragma unroll
    for (int mi = 0; mi < MI; ++mi)
#pragma unroll
      for (int ni = 0; ni < NI; ++ni)
#pragma unroll
        for (int r = 0; r < 4; ++r) {
          int lr = rbase0 + mi * 16 + rbase + r;
          int gi = m0 + lr;
          if (gi >= cnt) continue;
          int gc = n0 + cbase0 + ni * 16 + fr;
          if constexpr (DUAL) {
            float gv = acc1[mi][ni][r], uv = acc2[mi][ni][r];
            float sig = 1.0f / (1.0f + __expf(-gv));
            act[(size_t)(off + gi) * N + gc] = (bf16_t)(gv * sig * uv);
          } else {
            float v = acc1[mi][ni][r];
            if constexpr (SCALE) v *= wlist[(size_t)e * S_ + gi];
            C[(size_t)(off + gi) * N + gc] = (TC)v;
          }
        }
  }
}

// ---------------- Q/K head-RMSNorm + RoPE + bf16 hi/lo pack ----------------
__global__ __launch_bounds__(64) void qkpack_k(const float* __restrict__ qkv,
                                               const float* __restrict__ qn,
                                               const float* __restrict__ kn,
                                               const float* __restrict__ pe,
                                               bf16_t* __restrict__ Q2,
                                               bf16_t* __restrict__ K2) {
  int s = blockIdx.x, hh = blockIdx.y, lane = threadIdx.x;
  const float* ptr;
  const float* w;
  if (hh < NH_) { ptr = qkv + (size_t)s * QS_ + hh * HD_; w = qn; }
  else          { ptr = qkv + (size_t)s * QS_ + NH_ * HD_ + (hh - NH_) * HD_; w = kn; }
  float x0 = ptr[2 * lane], x1 = ptr[2 * lane + 1];
  float ss = x0 * x0 + x1 * x1;
#pragma unroll
  for (int m = 1; m < 64; m <<= 1) ss += __shfl_xor(ss, m);
  float inv = rsqrtf(ss * (1.0f / HD_) + EPS_);
  x0 = x0 * inv * w[2 * lane];
  x1 = x1 * inv * w[2 * lane + 1];
  float ang = pe[(size_t)s * (HD_ / 2) + lane];
  float sn, cs;
  sincosf(ang, &sn, &cs);
  float r0 = x0 * cs - x1 * sn;
  float r1 = x0 * sn + x1 * cs;
  if (hh < NH_) {
    const float scale = 0.08838834764831845f;
    float a = r0 * scale, b = r1 * scale;
    u16_t h0 = f2u(a), h1 = f2u(b);
    unsigned hw = (unsigned)h0 | ((unsigned)h1 << 16);
    unsigned lw = (unsigned)f2u(a - u2f(h0)) | ((unsigned)f2u(b - u2f(h1)) << 16);
    unsigned* base = (unsigned*)(Q2 + ((size_t)s * NH_ + hh) * 256);
    base[lane] = hw;
    base[64 + lane] = lw;
  } else {
    u16_t h0 = f2u(r0), h1 = f2u(r1);
    unsigned hw = (unsigned)h0 | ((unsigned)h1 << 16);
    unsigned lw = (unsigned)f2u(r0 - u2f(h0)) | ((unsigned)f2u(r1 - u2f(h1)) << 16);
    int j = lane >> 2, off = (2 * lane) & 7;
    unsigned* base = (unsigned*)(K2 + ((size_t)(hh - NH_) * S_ + s) * 256);
    base[(((j) ^ (s & 31)) * 8 + off) >> 1] = hw;
    base[(((16 + j) ^ (s & 31)) * 8 + off) >> 1] = lw;
  }
}

// ---------------- V pack: fp32 v -> per-tile transposed swizzled bf16 hi/lo ----------------
__global__ __launch_bounds__(256) void vpack_k(const float* __restrict__ qkv,
                                               bf16_t* __restrict__ V2T) {
  int t = blockIdx.x, kvh = blockIdx.y;
  int kv0 = t * 64;
  bf16_t* dst = V2T + (size_t)(kvh * 16 + t) * 128 * 128;
  const float* vbase = qkv + NH_ * HD_ + NKV_ * HD_ + kvh * HD_;
#pragma unroll
  for (int i = 0; i < 4; ++i) {
    int flat = threadIdx.x + i * 256;
    int kvp = flat >> 5, d4 = (flat & 31) * 4;
    const float* r0 = vbase + (size_t)(kv0 + 2 * kvp) * QS_ + d4;
    const float* r1 = r0 + QS_;
    f32x4 a = *(const f32x4*)r0;
    f32x4 b = *(const f32x4*)r1;
    int kvg = (2 * kvp) >> 3, sub = (2 * kvp) & 7;
#pragma unroll
    for (int e = 0; e < 4; ++e) {
      int d = d4 + e;
      int fsw = (d ^ (d >> 4)) & 15;
      u16_t ha = f2u(a[e]), hb = f2u(b[e]);
      unsigned hw = (unsigned)ha | ((unsigned)hb << 16);
      unsigned lw = (unsigned)f2u(a[e] - u2f(ha)) | ((unsigned)f2u(b[e] - u2f(hb)) << 16);
      unsigned* dd = (unsigned*)(dst + d * 128);
      dd[((kvg ^ fsw) * 8 + sub) >> 1] = hw;
      dd[(((8 + kvg) ^ fsw) * 8 + sub) >> 1] = lw;
    }
  }
}

// ---------------- attention v6: unsplit flash, direct normalized output ----------------
#define AKV 64
__global__ __launch_bounds__(512, 2) void attn6_k(const bf16_t* __restrict__ Q2,
                                                  const bf16_t* __restrict__ K2,
                                                  const bf16_t* __restrict__ V2T,
                                                  bf16_t* __restrict__ o) {
  int q0 = blockIdx.x * 32;
  int kvh = blockIdx.y;
  int tid = threadIdx.x, lane = tid & 63, w = tid >> 6;
  int g = lane >> 5, c32 = lane & 31;
  int h = kvh * 8 + w;
  int qrow = q0 + c32;
  int last_t = (q0 + 31) >> 6;
  __shared__ __align__(16) u16_t Kl[AKV * 256];   // 32KB
  __shared__ __align__(16) u16_t Vl[128 * 128];   // 32KB

  bf16x8 qh[8], ql[8];
  {
    const bf16_t* qp2 = Q2 + ((size_t)qrow * NH_ + h) * 256;
#pragma unroll
    for (int ks = 0; ks < 8; ++ks) {
      qh[ks] = *(const bf16x8*)(qp2 + g * 8 + ks * 16);
      ql[ks] = *(const bf16x8*)(qp2 + 128 + g * 8 + ks * 16);
    }
  }

  f32x16 accO[4] = {};
  float m = -3.0e38f, l = 0.f;

  for (int t = 0; t <= last_t; ++t) {
    int kv0 = t * AKV;
    __syncthreads();
    {
      const bf16_t* ksrc = K2 + ((size_t)kvh * S_ + kv0) * 256;
#pragma unroll
      for (int i = 0; i < 4; ++i) {
        int cbase = w * 64 + i * 512;
        gload16(ksrc + (size_t)(cbase + lane) * 8, (bf16_t*)&Kl[cbase * 8]);
      }
    }
    {
      const bf16_t* vsrc = V2T + (size_t)(kvh * 16 + t) * 128 * 128;
#pragma unroll
      for (int i = 0; i < 4; ++i) {
        int cbase = w * 64 + i * 512;
        gload16(vsrc + (size_t)(cbase + lane) * 8, (bf16_t*)&Vl[cbase * 8]);
      }
    }
    __syncthreads();

    f32x16 accS[2] = {};
#pragma unroll
    for (int ks = 0; ks < 8; ++ks) {
      int db = g * 8 + ks * 16;
#pragma unroll
      for (int mf = 0; mf < 2; ++mf) {
        int kvr = c32 + mf * 32;
        bf16x8 ah = *(const bf16x8*)&Kl[kvr * 256 + (((db >> 3)) ^ c32) * 8];
        bf16x8 al = *(const bf16x8*)&Kl[kvr * 256 + ((16 + (db >> 3)) ^ c32) * 8];
        accS[mf] = __builtin_amdgcn_mfma_f32_32x32x16_bf16(ah, qh[ks], accS[mf], 0, 0, 0);
        accS[mf] = __builtin_amdgcn_mfma_f32_32x32x16_bf16(ah, ql[ks], accS[mf], 0, 0, 0);
        accS[mf] = __builtin_amdgcn_mfma_f32_32x32x16_bf16(al, qh[ks], accS[mf], 0, 0, 0);
      }
    }
    float p[2][16];
    float tmax = -3.0e38f;
#pragma unroll
    for (int mf = 0; mf < 2; ++mf)
#pragma unroll
      for (int r = 0; r < 16; ++r) {
        int kvg = kv0 + mf * 32 + (r & 3) + 8 * (r >> 2) + 4 * g;
        float s = (kvg <= qrow) ? accS[mf][r] : -3.0e38f;
        p[mf][r] = s;
        tmax = fmaxf(tmax, s);
      }
    tmax = fmaxf(tmax, __shfl_xor(tmax, 32));
    float mn = fmaxf(m, tmax);
    float sc = __expf(m - mn);
    float ts = 0.f;
#pragma unroll
    for (int mf = 0; mf < 2; ++mf)
#pragma unroll
      for (int r = 0; r < 16; ++r) {
        float e = __expf(p[mf][r] - mn);
        p[mf][r] = e;
        ts += e;
      }
    ts += __shfl_xor(ts, 32);
    l = l * sc + ts;
    m = mn;
#pragma unroll
    for (int r = 0; r < 16; ++r) {
      int row16 = (r & 3) + 8 * (r >> 2) + 4 * g;
      float scr = __shfl(sc, row16);
#pragma unroll
      for (int nf = 0; nf < 4; ++nf) accO[nf][r] *= scr;
    }
#pragma unroll
    for (int ks = 0; ks < 4; ++ks) {
      int k1 = ks & 1, mf = ks >> 1;
      unsigned Lh[4], Ll[4];
#pragma unroll
      for (int i = 0; i < 4; ++i) {
        float a = p[mf][8 * k1 + 2 * i], b = p[mf][8 * k1 + 2 * i + 1];
        u16_t ha = f2u(a), hb = f2u(b);
        Lh[i] = (unsigned)ha | ((unsigned)hb << 16);
        Ll[i] = (unsigned)f2u(a - u2f(ha)) | ((unsigned)f2u(b - u2f(hb)) << 16);
      }
      unsigned Xh[4], Xl[4];
#pragma unroll
      for (int i = 0; i < 4; ++i) {
        Xh[i] = (unsigned)__shfl_xor((int)Lh[i], 32);
        Xl[i] = (unsigned)__shfl_xor((int)Ll[i], 32);
      }
      uint4v fh, fl;
      fh[0] = g ? Xh[2] : Lh[0]; fh[1] = g ? Xh[3] : Lh[1];
      fh[2] = g ? Lh[2] : Xh[0]; fh[3] = g ? Lh[3] : Xh[1];
      fl[0] = g ? Xl[2] : Ll[0]; fl[1] = g ? Xl[3] : Ll[1];
      fl[2] = g ? Ll[2] : Xl[0]; fl[3] = g ? Ll[3] : Xl[1];
      bf16x8 pH = __builtin_bit_cast(bf16x8, fh);
      bf16x8 pL = __builtin_bit_cast(bf16x8, fl);
      int kvb = g * 8 + ks * 16;
#pragma unroll
      for (int nf = 0; nf < 4; ++nf) {
        int d = c32 + nf * 32;
        int fsw = (d ^ (d >> 4)) & 15;
        bf16x8 vh = *(const bf16x8*)&Vl[d * 128 + (((kvb >> 3)) ^ fsw) * 8];
        bf16x8 vl = *(const bf16x8*)&Vl[d * 128 + ((8 + (kvb >> 3)) ^ fsw) * 8];
        accO[nf] = __builtin_amdgcn_mfma_f32_32x32x16_bf16(pH, vh, accO[nf], 0, 0, 0);
        accO[nf] = __builtin_amdgcn_mfma_f32_32x32x16_bf16(pH, vl, accO[nf], 0, 0, 0);
        accO[nf] = __builtin_amdgcn_mfma_f32_32x32x16_bf16(pL, vh, accO[nf], 0, 0, 0);
      }
    }
  }
  float invl = 1.0f / l;
#pragma unroll
  for (int r = 0; r < 16; ++r) {
    int row16 = (r & 3) + 8 * (r >> 2) + 4 * g;
    float il = __shfl(invl, row16);
    int orow = q0 + row16;
#pragma unroll
    for (int nf = 0; nf < 4; ++nf)
      o[((size_t)orow * NH_ + h) * HD_ + nf * 32 + c32] = (bf16_t)(accO[nf][r] * il);
  }
}

// ---------------- router v2: parallel logits + wave-parallel top-8 (no atomics) ----------------
__global__ __launch_bounds__(256) void router2_k(const float* __restrict__ h2,
                                                 const float* __restrict__ gw,
                                                 int* __restrict__ sel,
                                                 float* __restrict__ wsel) {
  int t = blockIdx.x, tid = threadIdx.x;
  int e = tid & 31, grp = tid >> 5;
  float acc = 0.f;
  for (int kk = grp; kk < H_; kk += 8)
    acc += h2[(size_t)t * H_ + kk] * gw[(size_t)kk * NE_ + e];
  __shared__ float part[8][32];
  part[grp][e] = acc;
  __syncthreads();
  if (tid < 64) {
    int lane = tid;
    float lg = -3.0e38f;
    if (lane < 32) {
      lg = 0.f;
      for (int g = 0; g < 8; ++g) lg += part[g][lane];
    }
    float tm = lg;
#pragma unroll
    for (int mm = 1; mm < 32; mm <<= 1) tm = fmaxf(tm, __shfl_xor(tm, mm));
    if (lane < 32) lg = __expf(lg - tm);
    bool avail = (lane < 32);
    float tot = 0.f;
    int se[TOPK_]; float rw[TOPK_];
#pragma unroll
    for (int kk = 0; kk < TOPK_; ++kk) {
      float val = avail ? lg : -1.f;
      float best = val;
#pragma unroll
      for (int mm = 1; mm < 32; mm <<= 1) best = fmaxf(best, __shfl_xor(best, mm));
      unsigned long long ball = __ballot(avail && (val == best));
      int bi = (int)__builtin_ctzll(ball);
      if (lane == bi) avail = false;
      se[kk] = bi;
      rw[kk] = best;
      tot += best;
    }
    float itot = 1.0f / tot;
    if (lane == 0) {
#pragma unroll
      for (int kk = 0; kk < TOPK_; ++kk) {
        sel[t * TOPK_ + kk] = se[kk];
        wsel[t * TOPK_ + kk] = rw[kk] * itot;
      }
    }
  }
}

// ---------------- expert list build: 1 wave per expert, ballot prefix scan ----------------
__global__ __launch_bounds__(64) void build_k(const int* __restrict__ sel,
                                              const float* __restrict__ wsel,
                                              int* __restrict__ counts,
                                              int* __restrict__ toklist,
                                              float* __restrict__ wlist,
                                              int* __restrict__ pos) {
  int e = blockIdx.x, lane = threadIdx.x;
  int base = 0;
  for (int c = 0; c < S_ / 64; ++c) {
    int t = c * 64 + lane;
    int match = -1;
#pragma unroll
    for (int k = 0; k < TOPK_; ++k)
      if (sel[t * TOPK_ + k] == e) match = k;
    bool flag = (match >= 0);
    unsigned long long mask = __ballot(flag);
    int prefix = __popcll(mask & ((1ull << lane) - 1ull));
    if (flag) {
      int p = base + prefix;
      toklist[e * S_ + p] = t;
      wlist[e * S_ + p] = wsel[t * TOPK_ + match];
      pos[t * TOPK_ + match] = p;
    }
    base += __popcll(mask);
  }
  if (lane == 0) counts[e] = base;
}

// scan + build compacted (expert, m-tile) work list for BMT=256; zero queue heads
__global__ void scan_k(const int* __restrict__ counts, int* __restrict__ offsets,
                       int* __restrict__ mslots, int* __restrict__ meta,
                       int* __restrict__ qheads) {
  if (threadIdx.x == 0 && blockIdx.x == 0) {
    int o = 0, ns = 0;
    for (int e = 0; e < NE_; ++e) {
      offsets[e] = o;
      int c = counts[e];
      for (int m0 = 0; m0 < c; m0 += 256) mslots[ns++] = (e << 8) | (m0 >> 8);
      o += c;
    }
    offsets[NE_] = o;
    meta[0] = ns;
    qheads[0] = 0;
    qheads[1] = 0;
  }
}

// ---------------- combine ----------------
__global__ __launch_bounds__(256) void combine_k(const float* __restrict__ x1,
                                                 const bf16_t* __restrict__ pairout,
                                                 const int* __restrict__ sel,
                                                 const int* __restrict__ pos,
                                                 const int* __restrict__ offsets,
                                                 float* __restrict__ out) {
  int t = blockIdx.x, tid = threadIdx.x;
  int slots[TOPK_];
#pragma unroll
  for (int kk = 0; kk < TOPK_; ++kk)
    slots[kk] = offsets[sel[t * TOPK_ + kk]] + pos[t * TOPK_ + kk];
  int c = tid * 8;
  f32x4 s0 = *(const f32x4*)(x1 + (size_t)t * H_ + c);
  f32x4 s1 = *(const f32x4*)(x1 + (size_t)t * H_ + c + 4);
#pragma unroll
  for (int kk = 0; kk < TOPK_; ++kk) {
    bf16x8 pv = *(const bf16x8*)(pairout + (size_t)slots[kk] * H_ + c);
#pragma unroll
    for (int i = 0; i < 4; ++i) { s0[i] += (float)pv[i]; s1[i] += (float)pv[i + 4]; }
  }
  *(f32x4*)(out + (size_t)t * H_ + c) = s0;
  *(f32x4*)(out + (size_t)t * H_ + c + 4) = s1;
}

extern "C" void kernel_launch(void* const* d_in, const int* in_sizes, int n_in,
                              void* d_out, int out_size, void* d_ws, size_t ws_size,
                              hipStream_t stream) {
  const float* hidden = (const float*)d_in[0];
  const float* pe     = (const float*)d_in[1];
  const float* ln1    = (const float*)d_in[4];
  const float* ln2    = (const float*)d_in[5];
  const float* q_w    = (const float*)d_in[6];
  const float* k_w    = (const float*)d_in[7];
  const float* v_w    = (const float*)d_in[8];
  const float* o_w    = (const float*)d_in[9];
  const float* qn     = (const float*)d_in[10];
  const float* kn     = (const float*)d_in[11];
  const float* gate_w = (const float*)d_in[12];
  const float* wg     = (const float*)d_in[13];
  const float* wu     = (const float*)d_in[14];
  const float* wd     = (const float*)d_in[15];
  float* out = (float*)d_out;

  char* p = (char*)d_ws;
  auto alloc = [&](size_t bytes) {
    char* r = p;
    p += (bytes + 255) & ~(size_t)255;
    return r;
  };
  bf16_t* h1b     = (bf16_t*)alloc((size_t)S_ * H_ * 2);
  float*  qkv     = (float*)alloc((size_t)S_ * QS_ * 4);
  bf16_t* Q2      = (bf16_t*)alloc((size_t)S_ * NH_ * 256 * 2);
  bf16_t* K2      = (bf16_t*)alloc((size_t)NKV_ * S_ * 256 * 2);
  bf16_t* V2T     = (bf16_t*)alloc((size_t)NKV_ * 16 * 128 * 128 * 2);
  bf16_t* aob     = (bf16_t*)alloc((size_t)S_ * NH_ * HD_ * 2);
  float*  x1      = (float*)alloc((size_t)S_ * H_ * 4);
  float*  h2      = (float*)alloc((size_t)S_ * H_ * 4);
  bf16_t* h2b     = (bf16_t*)alloc((size_t)S_ * H_ * 2);
  bf16_t* act     = (bf16_t*)alloc((size_t)S_ * TOPK_ * I_ * 2);
  bf16_t* po      = (bf16_t*)alloc((size_t)S_ * TOPK_ * H_ * 2);
  int*    counts  = (int*)alloc(NE_ * 4);
  int*    offs    = (int*)alloc((NE_ + 1) * 4);
  int*    toklist = (int*)alloc((size_t)NE_ * S_ * 4);
  float*  wlist   = (float*)alloc((size_t)NE_ * S_ * 4);
  int*    sel     = (int*)alloc((size_t)S_ * TOPK_ * 4);
  float*  wsel    = (float*)alloc((size_t)S_ * TOPK_ * 4);
  int*    pos     = (int*)alloc((size_t)S_ * TOPK_ * 4);
  int*    mslots  = (int*)alloc(512 * 4);
  int*    meta    = (int*)alloc(4);
  int*    qheads  = (int*)alloc(2 * 4);
  bf16_t* qkvT = (bf16_t*)alloc((size_t)QS_ * H_ * 2);
  bf16_t* owT  = (bf16_t*)alloc((size_t)(NH_ * HD_) * H_ * 2);
  bf16_t* wgT  = (bf16_t*)alloc((size_t)NE_ * H_ * I_ * 2);
  bf16_t* wuT  = (bf16_t*)alloc((size_t)NE_ * H_ * I_ * 2);
  bf16_t* wdT  = (bf16_t*)alloc((size_t)NE_ * I_ * H_ * 2);
  bf16_t* qwTp = qkvT;
  bf16_t* kwTp = qkvT + (size_t)(NH_ * HD_) * H_;
  bf16_t* vwTp = qkvT + (size_t)(NH_ * HD_ + NKV_ * HD_) * H_;

  transp3_k<<<dim3((NH_ * HD_) / 64, H_ / 64, 1), 256, 0, stream>>>(q_w, qwTp, H_, NH_ * HD_);
  transp3_k<<<dim3((NKV_ * HD_) / 64, H_ / 64, 1), 256, 0, stream>>>(k_w, kwTp, H_, NKV_ * HD_);
  transp3_k<<<dim3((NKV_ * HD_) / 64, H_ / 64, 1), 256, 0, stream>>>(v_w, vwTp, H_, NKV_ * HD_);
  transp3_k<<<dim3(H_ / 64, (NH_ * HD_) / 64, 1), 256, 0, stream>>>(o_w, owT, NH_ * HD_, H_);
  transp3_k<<<dim3(I_ / 64, H_ / 64, NE_), 256, 0, stream>>>(wg, wgT, H_, I_);
  transp3_k<<<dim3(I_ / 64, H_ / 64, NE_), 256, 0, stream>>>(wu, wuT, H_, I_);
  transp3_k<<<dim3(H_ / 64, I_ / 64, NE_), 256, 0, stream>>>(wd, wdT, I_, H_);

  rmsnorm2_k<false><<<S_, 256, 0, stream>>>(hidden, ln1, nullptr, h1b);
  // fused QKV projection: BK=128 deep issue, 128x128 tiles -> 320 blocks
  gemmd2_k<128, 2, 4, float, false>
      <<<dim3(S_ / 128, QS_ / 128), 512, 0, stream>>>(h1b, qkvT, nullptr, qkv, S_, QS_, H_);
  qkpack_k<<<dim3(S_, NH_ + NKV_), 64, 0, stream>>>(qkv, qn, kn, pe, Q2, K2);
  vpack_k<<<dim3(16, NKV_), 256, 0, stream>>>(qkv, V2T);
  // attention: unsplit flash, direct output (128 blocks, 8 heads/block)
  attn6_k<<<dim3(S_ / 32, NKV_), 512, 0, stream>>>(Q2, K2, V2T, aob);
  // O projection + residual: BK=128 deep issue, 128x64 tiles -> 256 blocks (WM4xWN2 = 8 waves)
  gemmd2_k<64, 4, 2, float, true>
      <<<dim3(S_ / 128, H_ / 64), 512, 0, stream>>>(aob, owT, hidden, x1, S_, H_, NH_ * HD_);
  rmsnorm2_k<true><<<S_, 256, 0, stream>>>(x1, ln2, h2, h2b);
  router2_k<<<S_, 256, 0, stream>>>(h2, gate_w, sel, wsel);
  build_k<<<NE_, 64, 0, stream>>>(sel, wsel, counts, toklist, wlist, pos);
  scan_k<<<1, 64, 0, stream>>>(counts, offs, mslots, meta, qheads);
  // MoE up (fused gate+up+silu): BMT=256 x 64 DUAL, BK=64, 48KB, 2 blocks/CU
  gemme5_k<64, float, true, false, true>
      <<<512, 512, 0, stream>>>(h2b, wgT, wuT, nullptr, act, wlist, counts, offs, toklist,
                                mslots, meta, &qheads[0], I_ / 64, I_, H_);
  // MoE down (+ routing weight scale): BMT=256 x 128, BK=64, 48KB, 2 blocks/CU
  gemme5_k<128, bf16_t, false, true, false>
      <<<512, 512, 0, stream>>>(act, wdT, nullptr, po, nullptr, wlist, counts, offs, nullptr,
                                mslots, meta, &qheads[1], H_ / 128, H_, I_);
  combine_k<<<S_, 256, 0, stream>>>(x1, po, sel, pos, offs, out);
}

// Round 22
// 679.565 us; speedup vs baseline: 1.0462x; 1.0462x over previous
//
#include <hip/hip_runtime.h>
#include <hip/hip_bf16.h>

#define S_ 1024
#define H_ 2048
#define NH_ 32
#define NKV_ 4
#define HD_ 128
#define NE_ 32
#define TOPK_ 8
#define I_ 768
#define EPS_ 1e-6f
#define QS_ 5120   // fused qkv row stride: 4096 q + 512 k + 512 v
#define BK2 32

typedef __bf16 bf16_t;
typedef __bf16 bf16x4v __attribute__((ext_vector_type(4)));
typedef __bf16 bf16x8 __attribute__((ext_vector_type(8)));
typedef float f32x4 __attribute__((ext_vector_type(4)));
typedef float f32x16 __attribute__((ext_vector_type(16)));
typedef unsigned short u16_t;
typedef unsigned int uint2v __attribute__((ext_vector_type(2)));
typedef unsigned int uint4v __attribute__((ext_vector_type(4)));

static __device__ __forceinline__ u16_t f2u(float x) {
  return __builtin_bit_cast(u16_t, (__bf16)x);
}
static __device__ __forceinline__ float u2f(u16_t u) {
  return (float)__builtin_bit_cast(__bf16, u);
}

// async global->LDS 16B per lane; dest wave-uniform base + lane*16
static __device__ __forceinline__ void gload16(const bf16_t* g, bf16_t* l) {
  __builtin_amdgcn_global_load_lds(
      (const __attribute__((address_space(1))) unsigned int*)g,
      (__attribute__((address_space(3))) unsigned int*)l, 16, 0, 0);
}

// per-lane element offset inside a 1KB [16][32] k-step tile (XOR chunk swizzle)
static __device__ __forceinline__ int tile_lane_off(int lane) {
  return (lane >> 2) * 32 + (((lane & 3) ^ ((lane >> 3) & 3)) << 3);
}

// ---------------- RMSNorm over H: fp32 (optional) + bf16 outputs ----------------
template <bool WF32>
__global__ __launch_bounds__(256) void rmsnorm2_k(const float* __restrict__ x,
                                                  const float* __restrict__ w,
                                                  float* __restrict__ outf,
                                                  bf16_t* __restrict__ outb) {
  int r = blockIdx.x, tid = threadIdx.x;
  const float* xr = x + (size_t)r * H_;
  f32x4 a = *(const f32x4*)(xr + tid * 8);
  f32x4 b = *(const f32x4*)(xr + tid * 8 + 4);
  float ss = 0.f;
#pragma unroll
  for (int i = 0; i < 4; ++i) ss += a[i] * a[i] + b[i] * b[i];
#pragma unroll
  for (int m = 1; m < 64; m <<= 1) ss += __shfl_xor(ss, m);
  __shared__ float wsum[4];
  if ((tid & 63) == 0) wsum[tid >> 6] = ss;
  __syncthreads();
  ss = wsum[0] + wsum[1] + wsum[2] + wsum[3];
  float inv = rsqrtf(ss * (1.0f / H_) + EPS_);
  f32x4 w0 = *(const f32x4*)(w + tid * 8);
  f32x4 w1 = *(const f32x4*)(w + tid * 8 + 4);
  f32x4 o0, o1;
#pragma unroll
  for (int i = 0; i < 4; ++i) { o0[i] = a[i] * inv * w0[i]; o1[i] = b[i] * inv * w1[i]; }
  if constexpr (WF32) {
    *(f32x4*)(outf + (size_t)r * H_ + tid * 8) = o0;
    *(f32x4*)(outf + (size_t)r * H_ + tid * 8 + 4) = o1;
  }
  bf16x8 ob;
#pragma unroll
  for (int i = 0; i < 4; ++i) { ob[i] = (__bf16)o0[i]; ob[i + 4] = (__bf16)o1[i]; }
  *(bf16x8*)(outb + (size_t)r * H_ + tid * 8) = ob;
}

// ---------------- weight transpose + bf16 + tile pack ----------------
// in[R][C] fp32 (R = K dim, C = N dim) -> out tiles [C/16][R/32][16][32] bf16.
__global__ __launch_bounds__(256) void transp3_k(const float* __restrict__ in,
                                                 bf16_t* __restrict__ out, int R, int C) {
  __shared__ float tile[64][65];  // [k][n]
  size_t z = (size_t)blockIdx.z * R * C;
  int tx = threadIdx.x & 15, ty = threadIdx.x >> 4;
  int r0 = blockIdx.y * 64, c0 = blockIdx.x * 64;
#pragma unroll
  for (int i = 0; i < 4; ++i) {
    f32x4 v = *(const f32x4*)(in + z + (size_t)(r0 + ty + i * 16) * C + c0 + tx * 4);
    tile[ty + i * 16][tx * 4 + 0] = v[0];
    tile[ty + i * 16][tx * 4 + 1] = v[1];
    tile[ty + i * 16][tx * 4 + 2] = v[2];
    tile[ty + i * 16][tx * 4 + 3] = v[3];
  }
  __syncthreads();
  int KT = R >> 5;
  int flat = threadIdx.x * 16;
  int lt = flat >> 9;
  int within = flat & 511;
  int nr = within >> 5;
  int kc = within & 31;
  int tn = lt >> 1, tk = lt & 1;
  bf16x8 o0, o1;
#pragma unroll
  for (int j = 0; j < 8; ++j) o0[j] = (bf16_t)tile[tk * 32 + kc + j][tn * 16 + nr];
#pragma unroll
  for (int j = 0; j < 8; ++j) o1[j] = (bf16_t)tile[tk * 32 + kc + 8 + j][tn * 16 + nr];
  size_t tidx = ((size_t)((c0 >> 4) + tn) * KT + (r0 >> 5) + tk) << 9;
  *(bf16x8*)(out + z + tidx + nr * 32 + kc) = o0;
  *(bf16x8*)(out + z + tidx + nr * 32 + kc + 8) = o1;
}

// ---------------- dense GEMM v2: BK=128 supersteps, deep issue ----------------
// BMT=128, 8 waves (WM*WN must equal 8); per superstep each wave issues gload16
// back-to-back, one barrier, 4 MFMA sub-steps (k order = former BK2 sequence).
template <int BNT, int WM, int WN, typename TC, bool RESID>
__global__ __launch_bounds__(512) void gemmd2_k(
    const bf16_t* __restrict__ A, const bf16_t* __restrict__ Bt,
    const float* __restrict__ resid, TC* __restrict__ C, int M, int N, int K) {
  constexpr int BMT = 128, SUBS = 4;
  constexpr int MI = BMT / WM / 16;
  constexpr int NI = BNT / WN / 16;
  constexpr int NBT = BNT / 16;   // B row-tiles (<=8)
  static_assert(WM * WN == 8, "8 waves");
  __shared__ __align__(16) bf16_t As[SUBS][BMT][BK2];   // 32KB
  __shared__ __align__(16) bf16_t Bs[SUBS][BNT][BK2];
  int tid = threadIdx.x, lane = tid & 63, w = tid >> 6;
  int m0 = blockIdx.x * BMT, n0 = blockIdx.y * BNT;
  int srow = lane >> 2;
  int schunk = ((lane & 3) ^ ((lane >> 3) & 3)) * 8;
  int tloff = tile_lane_off(lane);
  int fr = lane & 15, g = lane >> 4;
  int rk = (g ^ ((fr >> 1) & 3)) * 8;
  int wm = w / WN, wn = w % WN;
  int rbase0 = wm * (BMT / WM), cbase0 = wn * (BNT / WN);
  int KT = K >> 5;
  int SS = K >> 7;
  const bf16_t* asrc = A + (size_t)(m0 + w * 16 + srow) * K + schunk;
  bool hasB = (w < NBT);
  const bf16_t* bsrc = nullptr;
  if (hasB) bsrc = Bt + ((size_t)((n0 + w * 16) >> 4) * KT) * 512 + tloff;
  f32x4 acc[MI][NI] = {};
  for (int ss = 0; ss < SS; ++ss) {
    int kbase = ss * 128;
#pragma unroll
    for (int sub = 0; sub < SUBS; ++sub)
      gload16(asrc + kbase + sub * BK2, &As[sub][w * 16][0]);
    if (hasB) {
#pragma unroll
      for (int sub = 0; sub < SUBS; ++sub)
        gload16(bsrc + (size_t)(ss * SUBS + sub) * 512, &Bs[sub][w * 16][0]);
    }
    __syncthreads();
#pragma unroll
    for (int sub = 0; sub < SUBS; ++sub) {
      bf16x8 af[MI], bf[NI];
#pragma unroll
      for (int i = 0; i < MI; ++i) af[i] = *(const bf16x8*)&As[sub][rbase0 + i * 16 + fr][rk];
#pragma unroll
      for (int i = 0; i < NI; ++i) bf[i] = *(const bf16x8*)&Bs[sub][cbase0 + i * 16 + fr][rk];
#pragma unroll
      for (int mi = 0; mi < MI; ++mi)
#pragma unroll
        for (int ni = 0; ni < NI; ++ni)
          acc[mi][ni] = __builtin_amdgcn_mfma_f32_16x16x32_bf16(af[mi], bf[ni], acc[mi][ni], 0, 0, 0);
    }
    __syncthreads();
  }
  int rbase = g * 4;
#pragma unroll
  for (int mi = 0; mi < MI; ++mi)
#pragma unroll
    for (int ni = 0; ni < NI; ++ni)
#pragma unroll
      for (int r = 0; r < 4; ++r) {
        int gi = m0 + rbase0 + mi * 16 + rbase + r;
        int gc = n0 + cbase0 + ni * 16 + fr;
        float v = acc[mi][ni][r];
        if constexpr (RESID) v += resid[(size_t)gi * N + gc];
        C[(size_t)gi * N + gc] = (TC)v;
      }
}

// ---------------- persistent expert GEMM v4: BK=128 deep issue, 64KB LDS -> 2 blocks/CU ----------------
template <int BNT, int WM, int WN, typename TC, bool GATHER, bool SCALE, bool DUAL>
__global__ __launch_bounds__(512) void gemme4_k(
    const bf16_t* __restrict__ A, const bf16_t* __restrict__ B1g,
    const bf16_t* __restrict__ B2g, TC* __restrict__ C, bf16_t* __restrict__ act,
    const float* __restrict__ wlist, const int* __restrict__ counts,
    const int* __restrict__ offsets, const int* __restrict__ toklist,
    const int* __restrict__ mslots, const int* __restrict__ meta,
    int* __restrict__ qhead, int NTN, int N, int K) {
  constexpr int BMT = 128;
  constexpr int SUBS = 4;
  constexpr int MI = BMT / WM / 16;
  constexpr int NI = BNT / WN / 16;
  constexpr int BNTT = BNT * (DUAL ? 2 : 1);
  constexpr int NBT = BNTT / 16;
  constexpr int BPW = NBT / 8;
  static_assert(BPW * 8 == NBT, "B tile split");
  __shared__ __align__(16) bf16_t As[SUBS][BMT][BK2];   // 32KB
  __shared__ __align__(16) bf16_t Bs[SUBS][BNTT][BK2];  // 32KB
  __shared__ int s_w;
  int tid = threadIdx.x, lane = tid & 63, w = tid >> 6;
  int srow = lane >> 2;
  int schunk = ((lane & 3) ^ ((lane >> 3) & 3)) * 8;
  int tloff = tile_lane_off(lane);
  int fr = lane & 15, g = lane >> 4;
  int rk = (g ^ ((fr >> 1) & 3)) * 8;
  int wm = w / WN, wn = w % WN;
  int rbase0 = wm * (BMT / WM), cbase0 = wn * (BNT / WN);
  int KT = K >> 5;
  int SS = K >> 7;
  int total = meta[0] * NTN;
  for (;;) {
    if (tid == 0) s_w = atomicAdd(qhead, 1);
    __syncthreads();
    int wk = s_w;
    if (wk >= total) return;
    int ms = mslots[wk / NTN];
    int n0 = (wk % NTN) * BNT;
    int e = ms >> 8, m0 = (ms & 255) * BMT;
    int cnt = counts[e], off = offsets[e];
    size_t bs = (size_t)K * N;
    const bf16_t* B1 = B1g + (size_t)e * bs;
    const bf16_t* B2 = DUAL ? (B2g + (size_t)e * bs) : nullptr;
    const bf16_t* asrc;
    {
      int gr = min(m0 + w * 16 + srow, cnt - 1);
      size_t grow;
      if constexpr (GATHER) grow = (size_t)toklist[e * S_ + gr];
      else grow = (size_t)(off + gr);
      asrc = A + grow * (size_t)K + schunk;
    }
    const bf16_t* bsrc;
    int brow16 = w * 16;
    {
      const bf16_t* Bb = (brow16 < BNT) ? B1 : B2;
      int rr = (brow16 < BNT) ? brow16 : brow16 - BNT;
      bsrc = Bb + ((size_t)((n0 + rr) >> 4) * KT) * 512 + tloff;
    }
    f32x4 acc1[MI][NI] = {};
    f32x4 acc2[DUAL ? MI : 1][DUAL ? NI : 1] = {};
    for (int ss = 0; ss < SS; ++ss) {
      int kbase = ss * 128;
#pragma unroll
      for (int sub = 0; sub < SUBS; ++sub)
        gload16(asrc + kbase + sub * BK2, &As[sub][w * 16][0]);
#pragma unroll
      for (int sub = 0; sub < SUBS; ++sub)
        gload16(bsrc + (size_t)(ss * SUBS + sub) * 512, &Bs[sub][brow16][0]);
      __syncthreads();
#pragma unroll
      for (int sub = 0; sub < SUBS; ++sub) {
        bf16x8 af[MI], b1f[NI], b2f[DUAL ? NI : 1];
#pragma unroll
        for (int i = 0; i < MI; ++i) af[i] = *(const bf16x8*)&As[sub][rbase0 + i * 16 + fr][rk];
#pragma unroll
        for (int i = 0; i < NI; ++i) b1f[i] = *(const bf16x8*)&Bs[sub][cbase0 + i * 16 + fr][rk];
        if constexpr (DUAL) {
#pragma unroll
          for (int i = 0; i < NI; ++i) b2f[i] = *(const bf16x8*)&Bs[sub][BNT + cbase0 + i * 16 + fr][rk];
        }
#pragma unroll
        for (int mi = 0; mi < MI; ++mi)
#pragma unroll
          for (int ni = 0; ni < NI; ++ni) {
            acc1[mi][ni] = __builtin_amdgcn_mfma_f32_16x16x32_bf16(af[mi], b1f[ni], acc1[mi][ni], 0, 0, 0);
            if constexpr (DUAL)
              acc2[mi][ni] = __builtin_amdgcn_mfma_f32_16x16x32_bf16(af[mi], b2f[ni], acc2[mi][ni], 0, 0, 0);
          }
      }
      __syncthreads();
    }
    int rbase = g * 4;
#pragma unroll
    for (int mi = 0; mi < MI; ++mi)
#pragma unroll
      for (int ni = 0; ni < NI; ++ni)
#pragma unroll
        for (int r = 0; r < 4; ++r) {
          int lr = rbase0 + mi * 16 + rbase + r;
          int gi = m0 + lr;
          if (gi >= cnt) continue;
          int gc = n0 + cbase0 + ni * 16 + fr;
          if constexpr (DUAL) {
            float gv = acc1[mi][ni][r], uv = acc2[mi][ni][r];
            float sig = 1.0f / (1.0f + __expf(-gv));
            act[(size_t)(off + gi) * N + gc] = (bf16_t)(gv * sig * uv);
          } else {
            float v = acc1[mi][ni][r];
            if constexpr (SCALE) v *= wlist[(size_t)e * S_ + gi];
            C[(size_t)(off + gi) * N + gc] = (TC)v;
          }
        }
  }
}

// ---------------- Q/K head-RMSNorm + RoPE + bf16 hi/lo pack ----------------
__global__ __launch_bounds__(64) void qkpack_k(const float* __restrict__ qkv,
                                               const float* __restrict__ qn,
                                               const float* __restrict__ kn,
                                               const float* __restrict__ pe,
                                               bf16_t* __restrict__ Q2,
                                               bf16_t* __restrict__ K2) {
  int s = blockIdx.x, hh = blockIdx.y, lane = threadIdx.x;
  const float* ptr;
  const float* w;
  if (hh < NH_) { ptr = qkv + (size_t)s * QS_ + hh * HD_; w = qn; }
  else          { ptr = qkv + (size_t)s * QS_ + NH_ * HD_ + (hh - NH_) * HD_; w = kn; }
  float x0 = ptr[2 * lane], x1 = ptr[2 * lane + 1];
  float ss = x0 * x0 + x1 * x1;
#pragma unroll
  for (int m = 1; m < 64; m <<= 1) ss += __shfl_xor(ss, m);
  float inv = rsqrtf(ss * (1.0f / HD_) + EPS_);
  x0 = x0 * inv * w[2 * lane];
  x1 = x1 * inv * w[2 * lane + 1];
  float ang = pe[(size_t)s * (HD_ / 2) + lane];
  float sn, cs;
  sincosf(ang, &sn, &cs);
  float r0 = x0 * cs - x1 * sn;
  float r1 = x0 * sn + x1 * cs;
  if (hh < NH_) {
    const float scale = 0.08838834764831845f;
    float a = r0 * scale, b = r1 * scale;
    u16_t h0 = f2u(a), h1 = f2u(b);
    unsigned hw = (unsigned)h0 | ((unsigned)h1 << 16);
    unsigned lw = (unsigned)f2u(a - u2f(h0)) | ((unsigned)f2u(b - u2f(h1)) << 16);
    unsigned* base = (unsigned*)(Q2 + ((size_t)s * NH_ + hh) * 256);
    base[lane] = hw;
    base[64 + lane] = lw;
  } else {
    u16_t h0 = f2u(r0), h1 = f2u(r1);
    unsigned hw = (unsigned)h0 | ((unsigned)h1 << 16);
    unsigned lw = (unsigned)f2u(r0 - u2f(h0)) | ((unsigned)f2u(r1 - u2f(h1)) << 16);
    int j = lane >> 2, off = (2 * lane) & 7;
    unsigned* base = (unsigned*)(K2 + ((size_t)(hh - NH_) * S_ + s) * 256);
    base[(((j) ^ (s & 31)) * 8 + off) >> 1] = hw;
    base[(((16 + j) ^ (s & 31)) * 8 + off) >> 1] = lw;
  }
}

// ---------------- V pack: fp32 v -> per-tile transposed swizzled bf16 hi/lo ----------------
__global__ __launch_bounds__(256) void vpack_k(const float* __restrict__ qkv,
                                               bf16_t* __restrict__ V2T) {
  int t = blockIdx.x, kvh = blockIdx.y;
  int kv0 = t * 64;
  bf16_t* dst = V2T + (size_t)(kvh * 16 + t) * 128 * 128;
  const float* vbase = qkv + NH_ * HD_ + NKV_ * HD_ + kvh * HD_;
#pragma unroll
  for (int i = 0; i < 4; ++i) {
    int flat = threadIdx.x + i * 256;
    int kvp = flat >> 5, d4 = (flat & 31) * 4;
    const float* r0 = vbase + (size_t)(kv0 + 2 * kvp) * QS_ + d4;
    const float* r1 = r0 + QS_;
    f32x4 a = *(const f32x4*)r0;
    f32x4 b = *(const f32x4*)r1;
    int kvg = (2 * kvp) >> 3, sub = (2 * kvp) & 7;
#pragma unroll
    for (int e = 0; e < 4; ++e) {
      int d = d4 + e;
      int fsw = (d ^ (d >> 4)) & 15;
      u16_t ha = f2u(a[e]), hb = f2u(b[e]);
      unsigned hw = (unsigned)ha | ((unsigned)hb << 16);
      unsigned lw = (unsigned)f2u(a[e] - u2f(ha)) | ((unsigned)f2u(b[e] - u2f(hb)) << 16);
      unsigned* dd = (unsigned*)(dst + d * 128);
      dd[((kvg ^ fsw) * 8 + sub) >> 1] = hw;
      dd[(((8 + kvg) ^ fsw) * 8 + sub) >> 1] = lw;
    }
  }
}

// ---------------- attention v6: unsplit flash, direct normalized output ----------------
#define AKV 64
__global__ __launch_bounds__(512, 2) void attn6_k(const bf16_t* __restrict__ Q2,
                                                  const bf16_t* __restrict__ K2,
                                                  const bf16_t* __restrict__ V2T,
                                                  bf16_t* __restrict__ o) {
  int q0 = blockIdx.x * 32;
  int kvh = blockIdx.y;
  int tid = threadIdx.x, lane = tid & 63, w = tid >> 6;
  int g = lane >> 5, c32 = lane & 31;
  int h = kvh * 8 + w;
  int qrow = q0 + c32;
  int last_t = (q0 + 31) >> 6;
  __shared__ __align__(16) u16_t Kl[AKV * 256];   // 32KB
  __shared__ __align__(16) u16_t Vl[128 * 128];   // 32KB

  bf16x8 qh[8], ql[8];
  {
    const bf16_t* qp2 = Q2 + ((size_t)qrow * NH_ + h) * 256;
#pragma unroll
    for (int ks = 0; ks < 8; ++ks) {
      qh[ks] = *(const bf16x8*)(qp2 + g * 8 + ks * 16);
      ql[ks] = *(const bf16x8*)(qp2 + 128 + g * 8 + ks * 16);
    }
  }

  f32x16 accO[4] = {};
  float m = -3.0e38f, l = 0.f;

  for (int t = 0; t <= last_t; ++t) {
    int kv0 = t * AKV;
    __syncthreads();
    {
      const bf16_t* ksrc = K2 + ((size_t)kvh * S_ + kv0) * 256;
#pragma unroll
      for (int i = 0; i < 4; ++i) {
        int cbase = w * 64 + i * 512;
        gload16(ksrc + (size_t)(cbase + lane) * 8, (bf16_t*)&Kl[cbase * 8]);
      }
    }
    {
      const bf16_t* vsrc = V2T + (size_t)(kvh * 16 + t) * 128 * 128;
#pragma unroll
      for (int i = 0; i < 4; ++i) {
        int cbase = w * 64 + i * 512;
        gload16(vsrc + (size_t)(cbase + lane) * 8, (bf16_t*)&Vl[cbase * 8]);
      }
    }
    __syncthreads();

    f32x16 accS[2] = {};
#pragma unroll
    for (int ks = 0; ks < 8; ++ks) {
      int db = g * 8 + ks * 16;
#pragma unroll
      for (int mf = 0; mf < 2; ++mf) {
        int kvr = c32 + mf * 32;
        bf16x8 ah = *(const bf16x8*)&Kl[kvr * 256 + (((db >> 3)) ^ c32) * 8];
        bf16x8 al = *(const bf16x8*)&Kl[kvr * 256 + ((16 + (db >> 3)) ^ c32) * 8];
        accS[mf] = __builtin_amdgcn_mfma_f32_32x32x16_bf16(ah, qh[ks], accS[mf], 0, 0, 0);
        accS[mf] = __builtin_amdgcn_mfma_f32_32x32x16_bf16(ah, ql[ks], accS[mf], 0, 0, 0);
        accS[mf] = __builtin_amdgcn_mfma_f32_32x32x16_bf16(al, qh[ks], accS[mf], 0, 0, 0);
      }
    }
    float p[2][16];
    float tmax = -3.0e38f;
#pragma unroll
    for (int mf = 0; mf < 2; ++mf)
#pragma unroll
      for (int r = 0; r < 16; ++r) {
        int kvg = kv0 + mf * 32 + (r & 3) + 8 * (r >> 2) + 4 * g;
        float s = (kvg <= qrow) ? accS[mf][r] : -3.0e38f;
        p[mf][r] = s;
        tmax = fmaxf(tmax, s);
      }
    tmax = fmaxf(tmax, __shfl_xor(tmax, 32));
    float mn = fmaxf(m, tmax);
    float sc = __expf(m - mn);
    float ts = 0.f;
#pragma unroll
    for (int mf = 0; mf < 2; ++mf)
#pragma unroll
      for (int r = 0; r < 16; ++r) {
        float e = __expf(p[mf][r] - mn);
        p[mf][r] = e;
        ts += e;
      }
    ts += __shfl_xor(ts, 32);
    l = l * sc + ts;
    m = mn;
#pragma unroll
    for (int r = 0; r < 16; ++r) {
      int row16 = (r & 3) + 8 * (r >> 2) + 4 * g;
      float scr = __shfl(sc, row16);
#pragma unroll
      for (int nf = 0; nf < 4; ++nf) accO[nf][r] *= scr;
    }
#pragma unroll
    for (int ks = 0; ks < 4; ++ks) {
      int k1 = ks & 1, mf = ks >> 1;
      unsigned Lh[4], Ll[4];
#pragma unroll
      for (int i = 0; i < 4; ++i) {
        float a = p[mf][8 * k1 + 2 * i], b = p[mf][8 * k1 + 2 * i + 1];
        u16_t ha = f2u(a), hb = f2u(b);
        Lh[i] = (unsigned)ha | ((unsigned)hb << 16);
        Ll[i] = (unsigned)f2u(a - u2f(ha)) | ((unsigned)f2u(b - u2f(hb)) << 16);
      }
      unsigned Xh[4], Xl[4];
#pragma unroll
      for (int i = 0; i < 4; ++i) {
        Xh[i] = (unsigned)__shfl_xor((int)Lh[i], 32);
        Xl[i] = (unsigned)__shfl_xor((int)Ll[i], 32);
      }
      uint4v fh, fl;
      fh[0] = g ? Xh[2] : Lh[0]; fh[1] = g ? Xh[3] : Lh[1];
      fh[2] = g ? Lh[2] : Xh[0]; fh[3] = g ? Lh[3] : Xh[1];
      fl[0] = g ? Xl[2] : Ll[0]; fl[1] = g ? Xl[3] : Ll[1];
      fl[2] = g ? Ll[2] : Xl[0]; fl[3] = g ? Ll[3] : Xl[1];
      bf16x8 pH = __builtin_bit_cast(bf16x8, fh);
      bf16x8 pL = __builtin_bit_cast(bf16x8, fl);
      int kvb = g * 8 + ks * 16;
#pragma unroll
      for (int nf = 0; nf < 4; ++nf) {
        int d = c32 + nf * 32;
        int fsw = (d ^ (d >> 4)) & 15;
        bf16x8 vh = *(const bf16x8*)&Vl[d * 128 + (((kvb >> 3)) ^ fsw) * 8];
        bf16x8 vl = *(const bf16x8*)&Vl[d * 128 + ((8 + (kvb >> 3)) ^ fsw) * 8];
        accO[nf] = __builtin_amdgcn_mfma_f32_32x32x16_bf16(pH, vh, accO[nf], 0, 0, 0);
        accO[nf] = __builtin_amdgcn_mfma_f32_32x32x16_bf16(pH, vl, accO[nf], 0, 0, 0);
        accO[nf] = __builtin_amdgcn_mfma_f32_32x32x16_bf16(pL, vh, accO[nf], 0, 0, 0);
      }
    }
  }
  float invl = 1.0f / l;
#pragma unroll
  for (int r = 0; r < 16; ++r) {
    int row16 = (r & 3) + 8 * (r >> 2) + 4 * g;
    float il = __shfl(invl, row16);
    int orow = q0 + row16;
#pragma unroll
    for (int nf = 0; nf < 4; ++nf)
      o[((size_t)orow * NH_ + h) * HD_ + nf * 32 + c32] = (bf16_t)(accO[nf][r] * il);
  }
}

// ---------------- router v2: parallel logits + wave-parallel top-8 (no atomics) ----------------
__global__ __launch_bounds__(256) void router2_k(const float* __restrict__ h2,
                                                 const float* __restrict__ gw,
                                                 int* __restrict__ sel,
                                                 float* __restrict__ wsel) {
  int t = blockIdx.x, tid = threadIdx.x;
  int e = tid & 31, grp = tid >> 5;
  float acc = 0.f;
  for (int kk = grp; kk < H_; kk += 8)
    acc += h2[(size_t)t * H_ + kk] * gw[(size_t)kk * NE_ + e];
  __shared__ float part[8][32];
  part[grp][e] = acc;
  __syncthreads();
  if (tid < 64) {
    int lane = tid;
    float lg = -3.0e38f;
    if (lane < 32) {
      lg = 0.f;
      for (int g = 0; g < 8; ++g) lg += part[g][lane];
    }
    float tm = lg;
#pragma unroll
    for (int mm = 1; mm < 32; mm <<= 1) tm = fmaxf(tm, __shfl_xor(tm, mm));
    if (lane < 32) lg = __expf(lg - tm);
    bool avail = (lane < 32);
    float tot = 0.f;
    int se[TOPK_]; float rw[TOPK_];
#pragma unroll
    for (int kk = 0; kk < TOPK_; ++kk) {
      float val = avail ? lg : -1.f;
      float best = val;
#pragma unroll
      for (int mm = 1; mm < 32; mm <<= 1) best = fmaxf(best, __shfl_xor(best, mm));
      unsigned long long ball = __ballot(avail && (val == best));
      int bi = (int)__builtin_ctzll(ball);
      if (lane == bi) avail = false;
      se[kk] = bi;
      rw[kk] = best;
      tot += best;
    }
    float itot = 1.0f / tot;
    if (lane == 0) {
#pragma unroll
      for (int kk = 0; kk < TOPK_; ++kk) {
        sel[t * TOPK_ + kk] = se[kk];
        wsel[t * TOPK_ + kk] = rw[kk] * itot;
      }
    }
  }
}

// ---------------- expert list build: 1 wave per expert, ballot prefix scan ----------------
__global__ __launch_bounds__(64) void build_k(const int* __restrict__ sel,
                                              const float* __restrict__ wsel,
                                              int* __restrict__ counts,
                                              int* __restrict__ toklist,
                                              float* __restrict__ wlist,
                                              int* __restrict__ pos) {
  int e = blockIdx.x, lane = threadIdx.x;
  int base = 0;
  for (int c = 0; c < S_ / 64; ++c) {
    int t = c * 64 + lane;
    int match = -1;
#pragma unroll
    for (int k = 0; k < TOPK_; ++k)
      if (sel[t * TOPK_ + k] == e) match = k;
    bool flag = (match >= 0);
    unsigned long long mask = __ballot(flag);
    int prefix = __popcll(mask & ((1ull << lane) - 1ull));
    if (flag) {
      int p = base + prefix;
      toklist[e * S_ + p] = t;
      wlist[e * S_ + p] = wsel[t * TOPK_ + match];
      pos[t * TOPK_ + match] = p;
    }
    base += __popcll(mask);
  }
  if (lane == 0) counts[e] = base;
}

// scan + build compacted (expert, m-tile) work list for BMT=128; zero queue heads
__global__ void scan_k(const int* __restrict__ counts, int* __restrict__ offsets,
                       int* __restrict__ mslots, int* __restrict__ meta,
                       int* __restrict__ qheads) {
  if (threadIdx.x == 0 && blockIdx.x == 0) {
    int o = 0, ns = 0;
    for (int e = 0; e < NE_; ++e) {
      offsets[e] = o;
      int c = counts[e];
      for (int m0 = 0; m0 < c; m0 += 128) mslots[ns++] = (e << 8) | (m0 >> 7);
      o += c;
    }
    offsets[NE_] = o;
    meta[0] = ns;
    qheads[0] = 0;
    qheads[1] = 0;
  }
}

// ---------------- combine ----------------
__global__ __launch_bounds__(256) void combine_k(const float* __restrict__ x1,
                                                 const bf16_t* __restrict__ pairout,
                                                 const int* __restrict__ sel,
                                                 const int* __restrict__ pos,
                                                 const int* __restrict__ offsets,
                                                 float* __restrict__ out) {
  int t = blockIdx.x, tid = threadIdx.x;
  int slots[TOPK_];
#pragma unroll
  for (int kk = 0; kk < TOPK_; ++kk)
    slots[kk] = offsets[sel[t * TOPK_ + kk]] + pos[t * TOPK_ + kk];
  int c = tid * 8;
  f32x4 s0 = *(const f32x4*)(x1 + (size_t)t * H_ + c);
  f32x4 s1 = *(const f32x4*)(x1 + (size_t)t * H_ + c + 4);
#pragma unroll
  for (int kk = 0; kk < TOPK_; ++kk) {
    bf16x8 pv = *(const bf16x8*)(pairout + (size_t)slots[kk] * H_ + c);
#pragma unroll
    for (int i = 0; i < 4; ++i) { s0[i] += (float)pv[i]; s1[i] += (float)pv[i + 4]; }
  }
  *(f32x4*)(out + (size_t)t * H_ + c) = s0;
  *(f32x4*)(out + (size_t)t * H_ + c + 4) = s1;
}

extern "C" void kernel_launch(void* const* d_in, const int* in_sizes, int n_in,
                              void* d_out, int out_size, void* d_ws, size_t ws_size,
                              hipStream_t stream) {
  const float* hidden = (const float*)d_in[0];
  const float* pe     = (const float*)d_in[1];
  const float* ln1    = (const float*)d_in[4];
  const float* ln2    = (const float*)d_in[5];
  const float* q_w    = (const float*)d_in[6];
  const float* k_w    = (const float*)d_in[7];
  const float* v_w    = (const float*)d_in[8];
  const float* o_w    = (const float*)d_in[9];
  const float* qn     = (const float*)d_in[10];
  const float* kn     = (const float*)d_in[11];
  const float* gate_w = (const float*)d_in[12];
  const float* wg     = (const float*)d_in[13];
  const float* wu     = (const float*)d_in[14];
  const float* wd     = (const float*)d_in[15];
  float* out = (float*)d_out;

  char* p = (char*)d_ws;
  auto alloc = [&](size_t bytes) {
    char* r = p;
    p += (bytes + 255) & ~(size_t)255;
    return r;
  };
  bf16_t* h1b     = (bf16_t*)alloc((size_t)S_ * H_ * 2);
  float*  qkv     = (float*)alloc((size_t)S_ * QS_ * 4);
  bf16_t* Q2      = (bf16_t*)alloc((size_t)S_ * NH_ * 256 * 2);
  bf16_t* K2      = (bf16_t*)alloc((size_t)NKV_ * S_ * 256 * 2);
  bf16_t* V2T     = (bf16_t*)alloc((size_t)NKV_ * 16 * 128 * 128 * 2);
  bf16_t* aob     = (bf16_t*)alloc((size_t)S_ * NH_ * HD_ * 2);
  float*  x1      = (float*)alloc((size_t)S_ * H_ * 4);
  float*  h2      = (float*)alloc((size_t)S_ * H_ * 4);
  bf16_t* h2b     = (bf16_t*)alloc((size_t)S_ * H_ * 2);
  bf16_t* act     = (bf16_t*)alloc((size_t)S_ * TOPK_ * I_ * 2);
  bf16_t* po      = (bf16_t*)alloc((size_t)S_ * TOPK_ * H_ * 2);
  int*    counts  = (int*)alloc(NE_ * 4);
  int*    offs    = (int*)alloc((NE_ + 1) * 4);
  int*    toklist = (int*)alloc((size_t)NE_ * S_ * 4);
  float*  wlist   = (float*)alloc((size_t)NE_ * S_ * 4);
  int*    sel     = (int*)alloc((size_t)S_ * TOPK_ * 4);
  float*  wsel    = (float*)alloc((size_t)S_ * TOPK_ * 4);
  int*    pos     = (int*)alloc((size_t)S_ * TOPK_ * 4);
  int*    mslots  = (int*)alloc(512 * 4);
  int*    meta    = (int*)alloc(4);
  int*    qheads  = (int*)alloc(2 * 4);
  bf16_t* qkvT = (bf16_t*)alloc((size_t)QS_ * H_ * 2);
  bf16_t* owT  = (bf16_t*)alloc((size_t)(NH_ * HD_) * H_ * 2);
  bf16_t* wgT  = (bf16_t*)alloc((size_t)NE_ * H_ * I_ * 2);
  bf16_t* wuT  = (bf16_t*)alloc((size_t)NE_ * H_ * I_ * 2);
  bf16_t* wdT  = (bf16_t*)alloc((size_t)NE_ * I_ * H_ * 2);
  bf16_t* qwTp = qkvT;
  bf16_t* kwTp = qkvT + (size_t)(NH_ * HD_) * H_;
  bf16_t* vwTp = qkvT + (size_t)(NH_ * HD_ + NKV_ * HD_) * H_;

  transp3_k<<<dim3((NH_ * HD_) / 64, H_ / 64, 1), 256, 0, stream>>>(q_w, qwTp, H_, NH_ * HD_);
  transp3_k<<<dim3((NKV_ * HD_) / 64, H_ / 64, 1), 256, 0, stream>>>(k_w, kwTp, H_, NKV_ * HD_);
  transp3_k<<<dim3((NKV_ * HD_) / 64, H_ / 64, 1), 256, 0, stream>>>(v_w, vwTp, H_, NKV_ * HD_);
  transp3_k<<<dim3(H_ / 64, (NH_ * HD_) / 64, 1), 256, 0, stream>>>(o_w, owT, NH_ * HD_, H_);
  transp3_k<<<dim3(I_ / 64, H_ / 64, NE_), 256, 0, stream>>>(wg, wgT, H_, I_);
  transp3_k<<<dim3(I_ / 64, H_ / 64, NE_), 256, 0, stream>>>(wu, wuT, H_, I_);
  transp3_k<<<dim3(H_ / 64, I_ / 64, NE_), 256, 0, stream>>>(wd, wdT, I_, H_);

  rmsnorm2_k<false><<<S_, 256, 0, stream>>>(hidden, ln1, nullptr, h1b);
  // fused QKV projection: BK=128 deep issue, 128x128 tiles -> 320 blocks
  gemmd2_k<128, 2, 4, float, false>
      <<<dim3(S_ / 128, QS_ / 128), 512, 0, stream>>>(h1b, qkvT, nullptr, qkv, S_, QS_, H_);
  qkpack_k<<<dim3(S_, NH_ + NKV_), 64, 0, stream>>>(qkv, qn, kn, pe, Q2, K2);
  vpack_k<<<dim3(16, NKV_), 256, 0, stream>>>(qkv, V2T);
  // attention: unsplit flash, direct output (128 blocks, 8 heads/block)
  attn6_k<<<dim3(S_ / 32, NKV_), 512, 0, stream>>>(Q2, K2, V2T, aob);
  // O projection + residual: BK=128 deep issue, 128x64 tiles -> 256 blocks (WM4xWN2)
  gemmd2_k<64, 4, 2, float, true>
      <<<dim3(S_ / 128, H_ / 64), 512, 0, stream>>>(aob, owT, hidden, x1, S_, H_, NH_ * HD_);
  rmsnorm2_k<true><<<S_, 256, 0, stream>>>(x1, ln2, h2, h2b);
  router2_k<<<S_, 256, 0, stream>>>(h2, gate_w, sel, wsel);
  build_k<<<NE_, 64, 0, stream>>>(sel, wsel, counts, toklist, wlist, pos);
  scan_k<<<1, 64, 0, stream>>>(counts, offs, mslots, meta, qheads);
  // MoE up (fused gate+up+silu): 128x64 DUAL, BK=128 deep issue, 64KB -> 2 blocks/CU
  gemme4_k<64, 2, 4, float, true, false, true>
      <<<512, 512, 0, stream>>>(h2b, wgT, wuT, nullptr, act, wlist, counts, offs, toklist,
                                mslots, meta, &qheads[0], I_ / 64, I_, H_);
  // MoE down (+ routing weight scale): 128x128, BK=128 deep issue, 64KB -> 2 blocks/CU
  gemme4_k<128, 2, 4, bf16_t, false, true, false>
      <<<512, 512, 0, stream>>>(act, wdT, nullptr, po, nullptr, wlist, counts, offs, nullptr,
                                mslots, meta, &qheads[1], H_ / 128, H_, I_);
  combine_k<<<S_, 256, 0, stream>>>(x1, po, sel, pos, offs, out);
}